// Round 10
// baseline (795.538 us; speedup 1.0000x reference)
//
#include <hip/hip_runtime.h>

// F2FConv3d on MI355X.
// V11 = V6 (best, 666us) + FUSED BatchNorm tail (pass3 eliminated).
// contrib = (x ⊗ bary) @ Wflat  as f16 MFMA (16x16x32), W = A-operand in registers (AGPRs).
// K ordering: p = kbasis*64 + i  (chunk c of 32: kbasis = c>>1, i = (c&1)*32 + [0,32)).
// Wave w owns output channels [w*16, w*16+16): A-frags = 18 x half8 = 72 regs, loaded once.
//
// Pipeline (= V6, proven): 2 groups per buffer, 3-buffer rotation, SINGLE barrier per
// iter (stage(t) targets buffer read at t-1), depth-2 counted vmcnt, steady WAITV(9),
// never 0 in loop. X staged via global_load_lds with READ-LINEAR LDS layout (the
// permutation lives in the per-lane global src address) -> conflict-free ds_read_b128.
//
// Fused BN: grid 768 @ launch_bounds(256,3) + 29KB LDS -> exactly 3 blocks/CU, ALL
// resident (measured occupancy ~33% = 12 waves/CU confirms). After stats atomics:
// per-wave vmcnt drain -> block increments device-scope done counter (release) ->
// tid0 spins (acquire, bounded) until 768 -> each block normalizes ITS OWN OUT slice
// (self-written -> L1/L2-warm; avoids pass3's 204MB HBM round-trip + launch gap).
//
// D layout (measured, m89): row = quad*4 + reg (channel), col = lane&15 (texture)
//   -> facet (4 consecutive textures) = shfl_xor 1,2 across lanes.

typedef _Float16 half8  __attribute__((ext_vector_type(8)));
typedef _Float16 h2     __attribute__((ext_vector_type(2)));
typedef __fp16   fp16x2 __attribute__((ext_vector_type(2)));
typedef float    f32x4  __attribute__((ext_vector_type(4)));
typedef float    f32x2  __attribute__((ext_vector_type(2)));

#define NGROUPS 100000   // 1.6M textures / 16 per group
#define NPAIRS  50000    // groups staged in pairs (8KB X contiguous)
#define FFACETS 400000
#define GRID1   768      // 3 blocks/CU x 256 CUs, exactly resident
#define LDSP    9472     // per buffer: X[0,8192) | BARY[8192,9344) | NTEX[9344,9376)

#define WAITV(N) asm volatile("s_waitcnt vmcnt(" #N ")" ::: "memory")
#define WAITL0() asm volatile("s_waitcnt lgkmcnt(0)" ::: "memory")
#define FENCE()  asm volatile("" ::: "memory")
#define SB0()    __builtin_amdgcn_sched_barrier(0)

union H8 { h2 h[4]; half8 v; };

static __device__ __forceinline__ h2 pkrtz(float a, float b) {
    fp16x2 r = __builtin_amdgcn_cvt_pkrtz(a, b);
    return __builtin_bit_cast(h2, r);
}

static __device__ __forceinline__ void gload16(const void* g, void* l) {
    __builtin_amdgcn_global_load_lds((const __attribute__((address_space(1))) void*)g,
                                     (__attribute__((address_space(3))) void*)l, 16, 0, 0);
}

// ---- kernel 1: swizzle W (fp32 [64][64][9]) -> f16 fragment order in ws, zero stats+done
__global__ __launch_bounds__(256) void prep_kernel(const float* __restrict__ W,
                                                   _Float16* __restrict__ wswz,
                                                   float* __restrict__ stats) {
    int idx = blockIdx.x * 256 + threadIdx.x;
    if (idx < 36864) {
        int j    = idx & 7;
        int lane = (idx >> 3) & 63;
        int mt   = (idx >> 9) & 3;        // which wave (channel tile)
        int c    = idx >> 11;             // K chunk 0..17
        int o    = mt * 16 + (lane & 15);
        int i    = (c & 1) * 32 + ((lane >> 4) << 3) + j;
        int kb   = c >> 1;
        wswz[idx] = (_Float16)W[(o * 64 + i) * 9 + kb];
    }
    if (idx < 132) stats[idx] = 0.0f;     // 128 stats + done counter (+pad)
}

// ---- kernel 2: fused GEMM + facet mean + bias + ReLU + BN stats + BN normalize
__global__ __launch_bounds__(256, 3) void pass1_kernel(
    const float* __restrict__ X, const float* __restrict__ BARY,
    const _Float16* __restrict__ WSWZ, const float* __restrict__ BIAS,
    const int* __restrict__ NTEX, float* __restrict__ OUT,
    float* __restrict__ stats, const float* __restrict__ GAMMA,
    const float* __restrict__ BETA) {

    __shared__ __align__(16) char ldsbuf[3 * LDSP];
    __shared__ float sl_s[64];
    __shared__ float sl_s2[64];

    const int tid  = threadIdx.x;
    const int wave = tid >> 6;
    const int lane = tid & 63;
    const int col  = lane & 15;   // texture within group / MFMA column
    const int quad = lane >> 4;

    // A-operand: this wave's 16 output channels, all K. 72 regs (AGPRs), resident whole kernel.
    half8 wf[18];
#pragma unroll
    for (int c = 0; c < 18; ++c)
        wf[c] = *(const half8*)(WSWZ + ((size_t)(c * 4 + wave) * 64 + lane) * 8);

    // bias for this lane's 4 channels: ch = wave*16 + quad*4 + r
    const f32x4 biasv = *(const f32x4*)(BIAS + wave * 16 + quad * 4);

    // ---- stage-side constants: linear LDS dest, permuted per-lane global src
    const int xdst = (wave << 10) + (lane << 4);             // dest byte within a 4KB half
    const int xsrc = ((lane & 15) << 8) + ((lane >> 4) << 5) // texture row + channel quad
                   + ((wave & 1) << 4) + ((wave >> 1) << 7); // wave covers (j&1)*16+(j>>1)*128
    const char* Xb  = (const char*)X;
    const char* BAb = (const char*)BARY;
    const char* NTb = (const char*)NTEX;

    // ---- read-side constants: X reads are lane-linear (conflict-free b128)
    const int xrd = lane << 4;
    const int bco = 8192 + col * 36;                         // 16 distinct banks, 4-way bcast
    const int nco = 9344 + ((col >> 2) << 2);

    float sacc[4]  = {0.f, 0.f, 0.f, 0.f};
    float s2acc[4] = {0.f, 0.f, 0.f, 0.f};

    const int b = blockIdx.x;
    const int n = (NPAIRS - 1 - b) / GRID1 + 1;              // pairs for this block (uniform)

    // 5 vmem ops per wave per STAGE (uniform across waves)
    auto STAGE = [&](char* S, int u) {
        const char* xs = Xb + (size_t)u * 8192;
        FENCE();
        gload16(xs + xsrc,        S + xdst);
        gload16(xs + 4096 + xsrc, S + 4096 + xdst);
        gload16(BAb + (size_t)u * 1152 + lane * 16, S + 8192 + lane * 16);
        if (lane < 8) gload16(BAb + (size_t)u * 1152 + 1024 + lane * 16, S + 9216 + lane * 16);
        if (lane < 2) gload16(NTb + (size_t)u * 32 + lane * 16,          S + 9344 + lane * 16);
        FENCE();
    };

    auto EPI = [&](f32x4 acc, float rc, int f) {
        f32x4 vv;
#pragma unroll
        for (int r = 0; r < 4; ++r) {
            float s = acc[r];
            s += __shfl_xor(s, 1);
            s += __shfl_xor(s, 2);
            s = s * rc + biasv[r];
            s = s > 0.f ? s : 0.f;
            vv[r] = s;
            sacc[r]  += s;         // every lane in the col-group holds same value:
            s2acc[r] += s * s;     // 4x overcount, corrected by 0.25 at the end
        }
        if ((col & 3) == 0)
            *(f32x4*)(OUT + (size_t)f * 64 + wave * 16 + quad * 4) = vv;
    };

    // ITER: [barrier][read buf L][stage into S][pack f16][36 MFMA][epilogue+stores]
    // Single barrier is safe: every wave consumes its ds_reads before reaching the NEXT
    // barrier, and S at iter t is the buffer that was read at t-1 (3-buffer rotation).
    auto ITER = [&](const char* L, char* S, int u, int upre, bool do_stage) {
        __builtin_amdgcn_s_barrier();          // caller did WAITV: stage(u) landed for all waves
        FENCE();
        // ---- LDS reads: 8x b128 lane-linear + 18x b32 bcast + 2x b32
        f32x4 r0[4], r1[4];
#pragma unroll
        for (int j = 0; j < 4; ++j) {
            r0[j] = *(const f32x4*)(L + (j << 10) + xrd);
            r1[j] = *(const f32x4*)(L + 4096 + (j << 10) + xrd);
        }
        float bF0[9], bF1[9];
#pragma unroll
        for (int k = 0; k < 9; ++k) bF0[k] = *(const float*)(L + bco + k * 4);
#pragma unroll
        for (int k = 0; k < 9; ++k) bF1[k] = *(const float*)(L + bco + 576 + k * 4);
        const int nt0 = *(const int*)(L + nco);
        const int nt1 = *(const int*)(L + nco + 16);

        if (do_stage) STAGE(S, upre);          // issued early; flies across 2 iterations

        // ---- convert current tiles to f16
        h2 xh0[8], xh1[8], bh0[9], bh1[9];
        xh0[0] = pkrtz(r0[0][0], r0[0][1]);  xh0[1] = pkrtz(r0[0][2], r0[0][3]);
        xh0[2] = pkrtz(r0[1][0], r0[1][1]);  xh0[3] = pkrtz(r0[1][2], r0[1][3]);
        xh0[4] = pkrtz(r0[2][0], r0[2][1]);  xh0[5] = pkrtz(r0[2][2], r0[2][3]);
        xh0[6] = pkrtz(r0[3][0], r0[3][1]);  xh0[7] = pkrtz(r0[3][2], r0[3][3]);
        xh1[0] = pkrtz(r1[0][0], r1[0][1]);  xh1[1] = pkrtz(r1[0][2], r1[0][3]);
        xh1[2] = pkrtz(r1[1][0], r1[1][1]);  xh1[3] = pkrtz(r1[1][2], r1[1][3]);
        xh1[4] = pkrtz(r1[2][0], r1[2][1]);  xh1[5] = pkrtz(r1[2][2], r1[2][3]);
        xh1[6] = pkrtz(r1[3][0], r1[3][1]);  xh1[7] = pkrtz(r1[3][2], r1[3][3]);
#pragma unroll
        for (int k = 0; k < 9; ++k) { bh0[k] = pkrtz(bF0[k], bF0[k]); bh1[k] = pkrtz(bF1[k], bF1[k]); }
        const float rc0 = __builtin_amdgcn_rcpf((float)nt0);   // exact for pow2 counts
        const float rc1 = __builtin_amdgcn_rcpf((float)nt1);

        // ---- 36 MFMAs as two independent 18-chains (g0/g1 interleaved)
        f32x4 accA = {0.f, 0.f, 0.f, 0.f};
        f32x4 accB = {0.f, 0.f, 0.f, 0.f};
        __builtin_amdgcn_s_setprio(1);
#pragma unroll
        for (int c = 0; c < 18; ++c) {
            const int hh = (c & 1) * 4;
            const h2 bkA = bh0[c >> 1];
            const h2 bkB = bh1[c >> 1];
            H8 fa, fb;
            fa.h[0] = xh0[hh + 0] * bkA;  fa.h[1] = xh0[hh + 1] * bkA;
            fa.h[2] = xh0[hh + 2] * bkA;  fa.h[3] = xh0[hh + 3] * bkA;
            accA = __builtin_amdgcn_mfma_f32_16x16x32_f16(wf[c], fa.v, accA, 0, 0, 0);
            fb.h[0] = xh1[hh + 0] * bkB;  fb.h[1] = xh1[hh + 1] * bkB;
            fb.h[2] = xh1[hh + 2] * bkB;  fb.h[3] = xh1[hh + 3] * bkB;
            accB = __builtin_amdgcn_mfma_f32_16x16x32_f16(wf[c], fb.v, accB, 0, 0, 0);
        }
        __builtin_amdgcn_s_setprio(0);

        // ---- facet mean + bias + ReLU + stats + store (facet = 4 adjacent lanes)
        const int f0 = u * 8 + (col >> 2);
        EPI(accA, rc0, f0);
        EPI(accB, rc1, f0 + 4);
    };

    char* B0 = ldsbuf;
    char* B1 = ldsbuf + LDSP;
    char* B2 = ldsbuf + 2 * LDSP;

    // ---- software pipeline: 3-buffer rotation, stage(t) -> buffer read at t-1
    STAGE(B0, b);
    STAGE(B1, b + GRID1);
    WAITV(5); ITER(B0, B2, b,         b + 2 * GRID1, true);   // also drains wf prologue loads
    WAITV(7); ITER(B1, B0, b + GRID1, b + 3 * GRID1, true);
    char *rd = B2, *st = B1, *ot = B0;
    int t = 2;
    for (; t < n - 2; ++t) {
        WAITV(9);
        ITER(rd, st, b + t * GRID1, b + (t + 2) * GRID1, true);
        char* tmp = ot; ot = st; st = rd; rd = tmp;
    }
    WAITV(9); ITER(rd, st, b + t * GRID1, 0, false);
    { char* tmp = ot; ot = st; st = rd; rd = tmp; } ++t;
    WAITV(4); ITER(rd, st, b + t * GRID1, 0, false);

    // reduce stats across the 16 cols; channels partitioned by (wave,quad,r)
#pragma unroll
    for (int r = 0; r < 4; ++r) {
        float s = sacc[r], s2 = s2acc[r];
        s  += __shfl_xor(s, 1);  s  += __shfl_xor(s, 2);
        s  += __shfl_xor(s, 4);  s  += __shfl_xor(s, 8);
        s2 += __shfl_xor(s2, 1); s2 += __shfl_xor(s2, 2);
        s2 += __shfl_xor(s2, 4); s2 += __shfl_xor(s2, 8);
        if (col == 0) {
            sl_s [wave * 16 + quad * 4 + r] = s  * 0.25f;
            sl_s2[wave * 16 + quad * 4 + r] = s2 * 0.25f;
        }
    }
    __syncthreads();
    if (tid < 64)        atomicAdd(&stats[tid],      sl_s [tid]);
    else if (tid < 128)  atomicAdd(&stats[tid],      sl_s2[tid - 64]);

    // ---- fused BN normalize (replaces pass3). Residency proven: 3 blk/CU x 256 CU = 768.
    int* done = (int*)(stats + 128);
    WAITV(0);                                  // own OUT stores + stats atomics complete
    __syncthreads();                           // all waves of this block drained
    if (tid == 0) {
        __hip_atomic_fetch_add(done, 1, __ATOMIC_RELEASE, __HIP_MEMORY_SCOPE_AGENT);
        int spins = 0;
        while (__hip_atomic_load(done, __ATOMIC_ACQUIRE, __HIP_MEMORY_SCOPE_AGENT) < GRID1
               && spins < (1 << 30)) { ++spins; __builtin_amdgcn_s_sleep(8); }
    }
    __syncthreads();

    const int ch0 = (tid * 2) & 63;            // even channel; ch1 = ch0+1
    const float invF = 1.0f / (float)FFACETS;
    float s1a = __hip_atomic_load(&stats[ch0],          __ATOMIC_RELAXED, __HIP_MEMORY_SCOPE_AGENT);
    float s2a = __hip_atomic_load(&stats[64 + ch0],     __ATOMIC_RELAXED, __HIP_MEMORY_SCOPE_AGENT);
    float s1b = __hip_atomic_load(&stats[ch0 + 1],      __ATOMIC_RELAXED, __HIP_MEMORY_SCOPE_AGENT);
    float s2b = __hip_atomic_load(&stats[64 + ch0 + 1], __ATOMIC_RELAXED, __HIP_MEMORY_SCOPE_AGENT);
    const float mu0 = s1a * invF, va0 = s2a * invF - mu0 * mu0;
    const float mu1 = s1b * invF, va1 = s2b * invF - mu1 * mu1;
    const float sc0 = rsqrtf(va0 + 1e-3f) * GAMMA[ch0],     be0 = BETA[ch0];
    const float sc1 = rsqrtf(va1 + 1e-3f) * GAMMA[ch0 + 1], be1 = BETA[ch0 + 1];

    // normalize this block's own OUT slice (pairs u = b, b+GRID1, ...; 512 f32 per pair)
    for (int u = b; u < NPAIRS; u += GRID1) {
        float* p = OUT + (size_t)u * 512 + tid * 2;
        f32x2 v = *(f32x2*)p;
        v[0] = (v[0] - mu0) * sc0 + be0;
        v[1] = (v[1] - mu1) * sc1 + be1;
        *(f32x2*)p = v;
    }
}

extern "C" void kernel_launch(void* const* d_in, const int* in_sizes, int n_in,
                              void* d_out, int out_size, void* d_ws, size_t ws_size,
                              hipStream_t stream) {
    const float* X     = (const float*)d_in[0];
    const float* BARY  = (const float*)d_in[1];
    const float* W     = (const float*)d_in[2];
    const float* BIAS  = (const float*)d_in[3];
    const float* GAMMA = (const float*)d_in[4];
    const float* BETA  = (const float*)d_in[5];
    const int*   NTEX  = (const int*)d_in[6];
    float* OUT = (float*)d_out;

    _Float16* wswz = (_Float16*)d_ws;                       // 73728 B
    float* stats   = (float*)((char*)d_ws + 73728);         // 128 stats + done counter

    prep_kernel<<<144, 256, 0, stream>>>(W, wswz, stats);
    pass1_kernel<<<GRID1, 256, 0, stream>>>(X, BARY, wswz, BIAS, NTEX, OUT, stats, GAMMA, BETA);
}

// Round 11
// 787.626 us; speedup vs baseline: 1.0100x; 1.0100x over previous
//
#include <hip/hip_runtime.h>

// F2FConv3d on MI355X.
// V12 = V6 pipeline + X staged in LDS as F16 (halves the dominant LDS-read term;
// DS pipe measured-model ~95% saturated in V6).
//   - iter t: issue 2x global_load_dwordx4 (X f32, pair t+2) into regs (T14 split)
//   - iter t+1: counted WAITV -> 4x pkrtz -> 1x swizzled ds_write_b128 (f16 tile)
//   - iter t+2: read 4x ds_read_b128 per pair (was 8), fragments arrive as h2 pairs
//     directly -> the 16 read-side pkrtz per pair-iter are gone (net VALU -12/wave).
// XOR swizzle granule ^= (col&7) on BOTH write and read (rule 21): even 8-lane/slot
// spread = bandwidth-optimal. LDS/buffer 9.4KB -> 5.3KB.
// bary/NTEX staging + reads, EPI, stats, pass3: byte-identical to V6.
//
// vmcnt ladder (per-iter queue [Xg:2][bary:3][stores:2], 2 iters in flight):
//   steady: WAITV(9) before barrier (bary(t) landed), WAITV(10) mid-iter before
//   ds_write (Xg(t+1) arrived). Tail: 9 / mid 5 / final 4. vmcnt(0) prologue only.
//
// contrib = (x ⊗ bary) @ Wflat as f16 MFMA 16x16x32; wave w owns channels
// [w*16,w*16+16): A-frags = 18 x half8 = 72 AGPRs resident. 36 MFMAs as two
// independent 18-chains. D layout (m89): row = quad*4+reg, col = lane&15.

typedef _Float16 half8  __attribute__((ext_vector_type(8)));
typedef _Float16 h2     __attribute__((ext_vector_type(2)));
typedef __fp16   fp16x2 __attribute__((ext_vector_type(2)));
typedef float    f32x4  __attribute__((ext_vector_type(4)));

#define NGROUPS 100000   // 1.6M textures / 16 per group
#define NPAIRS  50000    // groups processed in pairs (8KB f32 X contiguous)
#define FFACETS 400000
#define GRID1   768      // 3 blocks/CU x 256 CUs, exactly resident
#define LDSP    5280     // per buffer: Xf16[0,4096) | BARY[4096,5248) | NTEX[5248,5280)

#define WAITV(N) asm volatile("s_waitcnt vmcnt(" #N ")" ::: "memory")
#define WAITL0() asm volatile("s_waitcnt lgkmcnt(0)" ::: "memory")
#define FENCE()  asm volatile("" ::: "memory")

union H8 { h2 h[4]; half8 v; };

static __device__ __forceinline__ h2 pkrtz(float a, float b) {
    fp16x2 r = __builtin_amdgcn_cvt_pkrtz(a, b);
    return __builtin_bit_cast(h2, r);
}

static __device__ __forceinline__ void gload16(const void* g, void* l) {
    __builtin_amdgcn_global_load_lds((const __attribute__((address_space(1))) void*)g,
                                     (__attribute__((address_space(3))) void*)l, 16, 0, 0);
}

// ---- kernel 1: swizzle W (fp32 [64][64][9]) -> f16 fragment order in ws, zero stats
__global__ __launch_bounds__(256) void prep_kernel(const float* __restrict__ W,
                                                   _Float16* __restrict__ wswz,
                                                   float* __restrict__ stats) {
    int idx = blockIdx.x * 256 + threadIdx.x;
    if (idx < 36864) {
        int j    = idx & 7;
        int lane = (idx >> 3) & 63;
        int mt   = (idx >> 9) & 3;        // which wave (channel tile)
        int c    = idx >> 11;             // K chunk 0..17
        int o    = mt * 16 + (lane & 15);
        int i    = (c & 1) * 32 + ((lane >> 4) << 3) + j;
        int kb   = c >> 1;
        wswz[idx] = (_Float16)W[(o * 64 + i) * 9 + kb];
    }
    if (idx < 128) stats[idx] = 0.0f;
}

// ---- kernel 2: fused GEMM + facet mean + bias + ReLU + BN-stat accumulation
__global__ __launch_bounds__(256, 3) void pass1_kernel(
    const float* __restrict__ X, const float* __restrict__ BARY,
    const _Float16* __restrict__ WSWZ, const float* __restrict__ BIAS,
    const int* __restrict__ NTEX, float* __restrict__ OUT,
    float* __restrict__ stats) {

    __shared__ __align__(16) char ldsbuf[3 * LDSP];
    __shared__ float sl_s[64];
    __shared__ float sl_s2[64];

    const int tid  = threadIdx.x;
    const int wave = tid >> 6;
    const int lane = tid & 63;
    const int col  = lane & 15;   // texture within group / MFMA column
    const int quad = lane >> 4;

    // A-operand: this wave's 16 output channels, all K. 72 AGPRs, resident whole kernel.
    half8 wf[18];
#pragma unroll
    for (int c = 0; c < 18; ++c)
        wf[c] = *(const half8*)(WSWZ + ((size_t)(c * 4 + wave) * 64 + lane) * 8);

    // bias for this lane's 4 channels: ch = wave*16 + quad*4 + r
    const f32x4 biasv = *(const f32x4*)(BIAS + wave * 16 + quad * 4);

    // ---- X stage-side constants
    //   global: lane covers bytes [u*8192 + wave*2048 + lane*32, +32) = texture
    //   tex = wave*8 + (lane>>3), channels ch = (lane&7)*8 .. +8
    const int xgsrc = (wave << 11) + (lane << 5);
    //   f16 tile dest: tex*128 + swizzled granule ((lane&7) ^ (tex&7))*16
    const int xtex  = (wave << 3) + (lane >> 3);
    const int xwr   = xtex * 128 + ((((lane & 7) ^ (xtex & 7))) << 4);
    const char* Xb  = (const char*)X;
    const char* BAb = (const char*)BARY;
    const char* NTb = (const char*)NTEX;

    // ---- X read-side constants (swizzle matches write side; even 8-lane/slot spread)
    const int xr0 = (col << 7) + (((quad    ) ^ (col & 7)) << 4);  // ch quad*8..+7 (low 32)
    const int xr1 = (col << 7) + (((4 | quad) ^ (col & 7)) << 4);  // ch 32+quad*8..+7
    const int bco = 4096 + col * 36;                               // 36B stride: conflict-free
    const int nco = 5248 + ((col >> 2) << 2);

    float sacc[4]  = {0.f, 0.f, 0.f, 0.f};
    float s2acc[4] = {0.f, 0.f, 0.f, 0.f};

    const int b = blockIdx.x;
    const int n = (NPAIRS - 1 - b) / GRID1 + 1;   // pairs for this block (65 or 66)

    // bary + ntex staging: 3 gload16 per wave (redundant across waves -> idempotent,
    // keeps per-wave vmcnt bookkeeping uniform). Linear LDS dest (gload_lds rule).
    auto STAGE = [&](char* S, int u) {
        FENCE();
        gload16(BAb + (size_t)u * 1152 + lane * 16, S + 4096 + lane * 16);
        if (lane < 8) gload16(BAb + (size_t)u * 1152 + 1024 + lane * 16, S + 5120 + lane * 16);
        if (lane < 2) gload16(NTb + (size_t)u * 32 + lane * 16,          S + 5248 + lane * 16);
        FENCE();
    };

    auto XISSUE = [&](int u, f32x4& a, f32x4& b2) {
        const char* xs = Xb + (size_t)u * 8192 + xgsrc;
        FENCE();
        a  = *(const f32x4*)(xs);
        b2 = *(const f32x4*)(xs + 16);
        FENCE();
    };

    auto XWRITE = [&](char* S, const f32x4& a, const f32x4& b2) {
        H8 w;
        w.h[0] = pkrtz(a[0],  a[1]);   w.h[1] = pkrtz(a[2],  a[3]);
        w.h[2] = pkrtz(b2[0], b2[1]);  w.h[3] = pkrtz(b2[2], b2[3]);
        FENCE();
        *(half8*)(S + xwr) = w.v;      // one ds_write_b128, swizzled dest
        FENCE();
    };

    auto EPI = [&](f32x4 acc, float rc, int f) {
        f32x4 vv;
#pragma unroll
        for (int r = 0; r < 4; ++r) {
            float s = acc[r];
            s += __shfl_xor(s, 1);
            s += __shfl_xor(s, 2);
            s = s * rc + biasv[r];
            s = s > 0.f ? s : 0.f;
            vv[r] = s;
            sacc[r]  += s;         // every lane in the col-group holds same value:
            s2acc[r] += s * s;     // 4x overcount, corrected by 0.25 at the end
        }
        if ((col & 3) == 0)
            *(f32x4*)(OUT + (size_t)f * 64 + wave * 16 + quad * 4) = vv;
    };

    // ITER: [barrier][read buf L (4 b128 f16 X + bary/nt)][issue Xg(t+2)+bary(t+2)]
    //       [WAITV(mid)+ds_write f16 X(t+1) into Sx][bary->h2][36 MFMA][EPI][WAITL0]
    // Buffers: L = B(t%3) read now; Sb = B((t+2)%3) bary-stage; Sx = B((t+1)%3) X-write.
    // All three distinct; Sx was last read at t-2 (drained via barriers). WAITL0 at end
    // makes this wave's ds_write visible to all waves after the next barrier.
    auto ITER = [&](const char* L, char* Sb, char* Sx, int u, int upre,
                    bool do_issue, int midwait, bool do_write,
                    f32x4& ca, f32x4& cb, f32x4& ia, f32x4& ib) {
        __builtin_amdgcn_s_barrier();
        FENCE();
        H8 e0 = *(const H8*)(L + xr0);          // group0 ch[quad*8..+7]  (4 h2)
        H8 o0 = *(const H8*)(L + xr1);          // group0 ch[32+quad*8..+7]
        H8 e1 = *(const H8*)(L + 2048 + xr0);   // group1
        H8 o1 = *(const H8*)(L + 2048 + xr1);
        float bF0[9], bF1[9];
#pragma unroll
        for (int k = 0; k < 9; ++k) bF0[k] = *(const float*)(L + bco + k * 4);
#pragma unroll
        for (int k = 0; k < 9; ++k) bF1[k] = *(const float*)(L + bco + 576 + k * 4);
        const int nt0 = *(const int*)(L + nco);
        const int nt1 = *(const int*)(L + nco + 16);

        if (do_issue) { XISSUE(upre, ia, ib); STAGE(Sb, upre); }

        if (do_write) {
            if (midwait == 10) { WAITV(10); } else { WAITV(5); }
            XWRITE(Sx, ca, cb);
        }

        // bary -> h2 (18 pkrtz); X fragments need NO conversion (already f16)
        h2 bh0[9], bh1[9];
#pragma unroll
        for (int k = 0; k < 9; ++k) { bh0[k] = pkrtz(bF0[k], bF0[k]); bh1[k] = pkrtz(bF1[k], bF1[k]); }
        const float rc0 = __builtin_amdgcn_rcpf((float)nt0);   // exact for pow2 counts
        const float rc1 = __builtin_amdgcn_rcpf((float)nt1);

        // ---- 36 MFMAs as two independent 18-chains (g0/g1 interleaved)
        f32x4 accA = {0.f, 0.f, 0.f, 0.f};
        f32x4 accB = {0.f, 0.f, 0.f, 0.f};
        __builtin_amdgcn_s_setprio(1);
#pragma unroll
        for (int c = 0; c < 18; ++c) {
            const h2 bkA = bh0[c >> 1];
            const h2 bkB = bh1[c >> 1];
            const H8& sA = (c & 1) ? o0 : e0;
            const H8& sB = (c & 1) ? o1 : e1;
            H8 fa, fb;
            fa.h[0] = sA.h[0] * bkA;  fa.h[1] = sA.h[1] * bkA;
            fa.h[2] = sA.h[2] * bkA;  fa.h[3] = sA.h[3] * bkA;
            accA = __builtin_amdgcn_mfma_f32_16x16x32_f16(wf[c], fa.v, accA, 0, 0, 0);
            fb.h[0] = sB.h[0] * bkB;  fb.h[1] = sB.h[1] * bkB;
            fb.h[2] = sB.h[2] * bkB;  fb.h[3] = sB.h[3] * bkB;
            accB = __builtin_amdgcn_mfma_f32_16x16x32_f16(wf[c], fb.v, accB, 0, 0, 0);
        }
        __builtin_amdgcn_s_setprio(0);

        // ---- facet mean + bias + ReLU + stats + store (facet = 4 adjacent lanes)
        const int f0 = u * 8 + (col >> 2);
        EPI(accA, rc0, f0);
        EPI(accB, rc1, f0 + 4);
        WAITL0();          // ds_write drained before this wave reaches the next barrier
    };

    char* B0 = ldsbuf;
    char* B1 = ldsbuf + LDSP;
    char* B2 = ldsbuf + 2 * LDSP;

    // ---- prologue: pairs 0,1 fully staged (one-time vmcnt(0) ~700cy, negligible)
    f32x4 xAa, xAb, xBa, xBb;                  // set A = even pairs, set B = odd pairs
    XISSUE(b, xAa, xAb);          STAGE(B0, b);
    XISSUE(b + GRID1, xBa, xBb);  STAGE(B1, b + GRID1);
    WAITV(0);
    XWRITE(B0, xAa, xAb);
    XWRITE(B1, xBa, xBb);
    WAITL0();

    // t=0: reads B0; issues pair2 -> set A; no ds_write (pair1 written in prologue)
    ITER(B0, B2, B1, b, b + 2 * GRID1, true, 0, false, xBa, xBb, xAa, xAb);
    // t=1: reads B1; issues pair3 -> B; writes pair2 (set A) into B2
    ITER(B1, B0, B2, b + GRID1, b + 3 * GRID1, true, 10, true, xAa, xAb, xBa, xBb);

    char *rd = B2, *st = B1, *ot = B0;         // at t=2: read B2, bary->B1, Xwrite->B0
    int t = 2;
    for (; t < n - 2; ++t) {
        WAITV(9);
        if (t & 1) ITER(rd, st, ot, b + t * GRID1, b + (t + 2) * GRID1, true, 10, true,
                        xAa, xAb, xBa, xBb);
        else       ITER(rd, st, ot, b + t * GRID1, b + (t + 2) * GRID1, true, 10, true,
                        xBa, xBb, xAa, xAb);
        char* tmp = ot; ot = st; st = rd; rd = tmp;
    }
    // t = n-2: no new issues; write pair n-1 (cons set = (t+1)&1)
    WAITV(9);
    if (t & 1) ITER(rd, st, ot, b + t * GRID1, 0, false, 5, true, xAa, xAb, xBa, xBb);
    else       ITER(rd, st, ot, b + t * GRID1, 0, false, 5, true, xBa, xBb, xAa, xAb);
    { char* tmp = ot; ot = st; st = rd; rd = tmp; } ++t;
    // t = n-1: final pair, nothing in flight but stores
    WAITV(4);
    ITER(rd, st, ot, b + t * GRID1, 0, false, 0, false, xAa, xAb, xBa, xBb);

    // reduce stats across the 16 cols; channels partitioned by (wave,quad,r)
#pragma unroll
    for (int r = 0; r < 4; ++r) {
        float s = sacc[r], s2 = s2acc[r];
        s  += __shfl_xor(s, 1);  s  += __shfl_xor(s, 2);
        s  += __shfl_xor(s, 4);  s  += __shfl_xor(s, 8);
        s2 += __shfl_xor(s2, 1); s2 += __shfl_xor(s2, 2);
        s2 += __shfl_xor(s2, 4); s2 += __shfl_xor(s2, 8);
        if (col == 0) {
            sl_s [wave * 16 + quad * 4 + r] = s  * 0.25f;
            sl_s2[wave * 16 + quad * 4 + r] = s2 * 0.25f;
        }
    }
    __syncthreads();
    if (tid < 64)        atomicAdd(&stats[tid],      sl_s [tid]);
    else if (tid < 128)  atomicAdd(&stats[tid],      sl_s2[tid - 64]);
}

// ---- kernel 3: in-place batch-norm normalize on OUT
__global__ __launch_bounds__(256) void pass3_kernel(float* __restrict__ OUT,
    const float* __restrict__ stats, const float* __restrict__ gamma,
    const float* __restrict__ beta) {
    const int tid = threadIdx.x;
    const size_t l = (size_t)blockIdx.x * 256 + tid;
    const int c0 = ((int)l & 15) * 4;     // grid*256 is a multiple of 16 -> constant per thread
    float mu[4], sc[4], be[4];
    const float invF = 1.0f / (float)FFACETS;
#pragma unroll
    for (int u = 0; u < 4; ++u) {
        int ch = c0 + u;
        float m  = stats[ch] * invF;
        float va = stats[64 + ch] * invF - m * m;
        mu[u] = m;
        sc[u] = rsqrtf(va + 1e-3f) * gamma[ch];
        be[u] = beta[ch];
    }
    const size_t n4 = (size_t)FFACETS * 16;
    for (size_t i = l; i < n4; i += (size_t)gridDim.x * 256) {
        f32x4 v = ((f32x4*)OUT)[i];
#pragma unroll
        for (int u = 0; u < 4; ++u)
            v[u] = (v[u] - mu[u]) * sc[u] + be[u];
        ((f32x4*)OUT)[i] = v;
    }
}

extern "C" void kernel_launch(void* const* d_in, const int* in_sizes, int n_in,
                              void* d_out, int out_size, void* d_ws, size_t ws_size,
                              hipStream_t stream) {
    const float* X     = (const float*)d_in[0];
    const float* BARY  = (const float*)d_in[1];
    const float* W     = (const float*)d_in[2];
    const float* BIAS  = (const float*)d_in[3];
    const float* GAMMA = (const float*)d_in[4];
    const float* BETA  = (const float*)d_in[5];
    const int*   NTEX  = (const int*)d_in[6];
    float* OUT = (float*)d_out;

    _Float16* wswz = (_Float16*)d_ws;                       // 73728 B
    float* stats   = (float*)((char*)d_ws + 73728);         // 128 floats

    prep_kernel<<<144, 256, 0, stream>>>(W, wswz, stats);
    pass1_kernel<<<GRID1, 256, 0, stream>>>(X, BARY, wswz, BIAS, NTEX, OUT, stats);
    pass3_kernel<<<2048, 256, 0, stream>>>(OUT, stats, GAMMA, BETA);
}

// Round 12
// 665.947 us; speedup vs baseline: 1.1946x; 1.1827x over previous
//
#include <hip/hip_runtime.h>

// F2FConv3d on MI355X.
// V13 = V6 (best, 666us) with ONE change: the facet-sum in EPI uses DPP quad_perm
// (VALU pipe) instead of __shfl_xor (ds_swizzle, DS pipe). DS accounting showed the
// DS pipe ~saturated in V6 (~2500cy/CU per pair-iter vs ~2400 wall); the 16
// ds_swizzle per wave-iter (~93cy) were the largest removable term. xor1 =
// quad_perm[1,0,3,2]=0xB1, xor2 = quad_perm[2,3,0,1]=0x4E — facet = 4 ADJACENT
// lanes, exactly the DPP quad granule. Everything else byte-identical to V6.
//
// contrib = (x ⊗ bary) @ Wflat  as f16 MFMA (16x16x32), W = A-operand in registers (AGPRs).
// K ordering: p = kbasis*64 + i  (chunk c of 32: kbasis = c>>1, i = (c&1)*32 + [0,32)).
// Wave w owns output channels [w*16, w*16+16): A-frags = 18 x half8 = 72 regs, loaded once.
//
// Pipeline (= V6): 2 groups per buffer, 3-buffer rotation, SINGLE barrier per iter
// (stage(t) targets buffer read at t-1), depth-2 counted vmcnt, steady WAITV(9),
// never 0 in loop. X staged via global_load_lds with READ-LINEAR LDS layout (the
// permutation lives in the per-lane global src address) -> conflict-free ds_read_b128.
//
// D layout (measured, m89): row = quad*4 + reg (channel), col = lane&15 (texture)
//   -> facet (4 consecutive textures) = DPP quad_perm xor1/xor2 across lanes.

typedef _Float16 half8  __attribute__((ext_vector_type(8)));
typedef _Float16 h2     __attribute__((ext_vector_type(2)));
typedef __fp16   fp16x2 __attribute__((ext_vector_type(2)));
typedef float    f32x4  __attribute__((ext_vector_type(4)));

#define NGROUPS 100000   // 1.6M textures / 16 per group
#define NPAIRS  50000    // groups staged in pairs (8KB X contiguous)
#define FFACETS 400000
#define GRID1   768      // 3 blocks/CU x 256 CUs, exactly resident
#define LDSP    9472     // per buffer: X[0,8192) | BARY[8192,9344) | NTEX[9344,9376)

#define WAITV(N) asm volatile("s_waitcnt vmcnt(" #N ")" ::: "memory")
#define FENCE()  asm volatile("" ::: "memory")

union H8 { h2 h[4]; half8 v; };

static __device__ __forceinline__ h2 pkrtz(float a, float b) {
    fp16x2 r = __builtin_amdgcn_cvt_pkrtz(a, b);
    return __builtin_bit_cast(h2, r);
}

// facet sum over the 4 adjacent lanes of a quad — VALU-pipe DPP, no DS traffic
static __device__ __forceinline__ float qsum(float s) {
    s += __builtin_bit_cast(float, __builtin_amdgcn_mov_dpp(
             __builtin_bit_cast(int, s), 0xB1, 0xF, 0xF, true));   // quad_perm [1,0,3,2]
    s += __builtin_bit_cast(float, __builtin_amdgcn_mov_dpp(
             __builtin_bit_cast(int, s), 0x4E, 0xF, 0xF, true));   // quad_perm [2,3,0,1]
    return s;
}

static __device__ __forceinline__ void gload16(const void* g, void* l) {
    __builtin_amdgcn_global_load_lds((const __attribute__((address_space(1))) void*)g,
                                     (__attribute__((address_space(3))) void*)l, 16, 0, 0);
}

// ---- kernel 1: swizzle W (fp32 [64][64][9]) -> f16 fragment order in ws, zero stats
__global__ __launch_bounds__(256) void prep_kernel(const float* __restrict__ W,
                                                   _Float16* __restrict__ wswz,
                                                   float* __restrict__ stats) {
    int idx = blockIdx.x * 256 + threadIdx.x;
    if (idx < 36864) {
        int j    = idx & 7;
        int lane = (idx >> 3) & 63;
        int mt   = (idx >> 9) & 3;        // which wave (channel tile)
        int c    = idx >> 11;             // K chunk 0..17
        int o    = mt * 16 + (lane & 15);
        int i    = (c & 1) * 32 + ((lane >> 4) << 3) + j;
        int kb   = c >> 1;
        wswz[idx] = (_Float16)W[(o * 64 + i) * 9 + kb];
    }
    if (idx < 128) stats[idx] = 0.0f;
}

// ---- kernel 2: fused GEMM + facet mean + bias + ReLU + BN-stat accumulation
__global__ __launch_bounds__(256, 3) void pass1_kernel(
    const float* __restrict__ X, const float* __restrict__ BARY,
    const _Float16* __restrict__ WSWZ, const float* __restrict__ BIAS,
    const int* __restrict__ NTEX, float* __restrict__ OUT,
    float* __restrict__ stats) {

    __shared__ __align__(16) char ldsbuf[3 * LDSP];
    __shared__ float sl_s[64];
    __shared__ float sl_s2[64];

    const int tid  = threadIdx.x;
    const int wave = tid >> 6;
    const int lane = tid & 63;
    const int col  = lane & 15;   // texture within group / MFMA column
    const int quad = lane >> 4;

    // A-operand: this wave's 16 output channels, all K. 72 regs (AGPRs), resident whole kernel.
    half8 wf[18];
#pragma unroll
    for (int c = 0; c < 18; ++c)
        wf[c] = *(const half8*)(WSWZ + ((size_t)(c * 4 + wave) * 64 + lane) * 8);

    // bias for this lane's 4 channels: ch = wave*16 + quad*4 + r
    const f32x4 biasv = *(const f32x4*)(BIAS + wave * 16 + quad * 4);

    // ---- stage-side constants: linear LDS dest, permuted per-lane global src
    const int xdst = (wave << 10) + (lane << 4);             // dest byte within a 4KB half
    const int xsrc = ((lane & 15) << 8) + ((lane >> 4) << 5) // texture row + channel quad
                   + ((wave & 1) << 4) + ((wave >> 1) << 7); // wave covers (j&1)*16+(j>>1)*128
    const char* Xb  = (const char*)X;
    const char* BAb = (const char*)BARY;
    const char* NTb = (const char*)NTEX;

    // ---- read-side constants: X reads are lane-linear (conflict-free b128)
    const int xrd = lane << 4;
    const int bco = 8192 + col * 36;                         // 16 distinct banks, 4-way bcast
    const int nco = 9344 + ((col >> 2) << 2);

    float sacc[4]  = {0.f, 0.f, 0.f, 0.f};
    float s2acc[4] = {0.f, 0.f, 0.f, 0.f};

    const int b = blockIdx.x;
    const int n = (NPAIRS - 1 - b) / GRID1 + 1;              // pairs for this block (uniform)

    // 5 vmem ops per wave per STAGE (uniform across waves)
    auto STAGE = [&](char* S, int u) {
        const char* xs = Xb + (size_t)u * 8192;
        FENCE();
        gload16(xs + xsrc,        S + xdst);
        gload16(xs + 4096 + xsrc, S + 4096 + xdst);
        gload16(BAb + (size_t)u * 1152 + lane * 16, S + 8192 + lane * 16);
        if (lane < 8) gload16(BAb + (size_t)u * 1152 + 1024 + lane * 16, S + 9216 + lane * 16);
        if (lane < 2) gload16(NTb + (size_t)u * 32 + lane * 16,          S + 9344 + lane * 16);
        FENCE();
    };

    auto EPI = [&](f32x4 acc, float rc, int f) {
        f32x4 vv;
#pragma unroll
        for (int r = 0; r < 4; ++r) {
            float s = qsum(acc[r]);           // DPP quad reduce (VALU), was 2x shfl_xor (DS)
            s = s * rc + biasv[r];
            s = s > 0.f ? s : 0.f;
            vv[r] = s;
            sacc[r]  += s;         // every lane in the col-group holds same value:
            s2acc[r] += s * s;     // 4x overcount, corrected by 0.25 at the end
        }
        if ((col & 3) == 0)
            *(f32x4*)(OUT + (size_t)f * 64 + wave * 16 + quad * 4) = vv;
    };

    // ITER: [barrier][read buf L][stage into S][pack f16][36 MFMA][epilogue+stores]
    // Single barrier is safe: every wave consumes its ds_reads before reaching the NEXT
    // barrier, and S at iter t is the buffer that was read at t-1 (3-buffer rotation).
    auto ITER = [&](const char* L, char* S, int u, int upre, bool do_stage) {
        __builtin_amdgcn_s_barrier();          // caller did WAITV: stage(u) landed for all waves
        FENCE();
        // ---- LDS reads: 8x b128 lane-linear + 18x b32 bcast + 2x b32
        f32x4 r0[4], r1[4];
#pragma unroll
        for (int j = 0; j < 4; ++j) {
            r0[j] = *(const f32x4*)(L + (j << 10) + xrd);
            r1[j] = *(const f32x4*)(L + 4096 + (j << 10) + xrd);
        }
        float bF0[9], bF1[9];
#pragma unroll
        for (int k = 0; k < 9; ++k) bF0[k] = *(const float*)(L + bco + k * 4);
#pragma unroll
        for (int k = 0; k < 9; ++k) bF1[k] = *(const float*)(L + bco + 576 + k * 4);
        const int nt0 = *(const int*)(L + nco);
        const int nt1 = *(const int*)(L + nco + 16);

        if (do_stage) STAGE(S, upre);          // issued early; flies across 2 iterations

        // ---- convert current tiles to f16
        h2 xh0[8], xh1[8], bh0[9], bh1[9];
        xh0[0] = pkrtz(r0[0][0], r0[0][1]);  xh0[1] = pkrtz(r0[0][2], r0[0][3]);
        xh0[2] = pkrtz(r0[1][0], r0[1][1]);  xh0[3] = pkrtz(r0[1][2], r0[1][3]);
        xh0[4] = pkrtz(r0[2][0], r0[2][1]);  xh0[5] = pkrtz(r0[2][2], r0[2][3]);
        xh0[6] = pkrtz(r0[3][0], r0[3][1]);  xh0[7] = pkrtz(r0[3][2], r0[3][3]);
        xh1[0] = pkrtz(r1[0][0], r1[0][1]);  xh1[1] = pkrtz(r1[0][2], r1[0][3]);
        xh1[2] = pkrtz(r1[1][0], r1[1][1]);  xh1[3] = pkrtz(r1[1][2], r1[1][3]);
        xh1[4] = pkrtz(r1[2][0], r1[2][1]);  xh1[5] = pkrtz(r1[2][2], r1[2][3]);
        xh1[6] = pkrtz(r1[3][0], r1[3][1]);  xh1[7] = pkrtz(r1[3][2], r1[3][3]);
#pragma unroll
        for (int k = 0; k < 9; ++k) { bh0[k] = pkrtz(bF0[k], bF0[k]); bh1[k] = pkrtz(bF1[k], bF1[k]); }
        const float rc0 = __builtin_amdgcn_rcpf((float)nt0);   // exact for pow2 counts
        const float rc1 = __builtin_amdgcn_rcpf((float)nt1);

        // ---- 36 MFMAs as two independent 18-chains (g0/g1 interleaved)
        f32x4 accA = {0.f, 0.f, 0.f, 0.f};
        f32x4 accB = {0.f, 0.f, 0.f, 0.f};
        __builtin_amdgcn_s_setprio(1);
#pragma unroll
        for (int c = 0; c < 18; ++c) {
            const int hh = (c & 1) * 4;
            const h2 bkA = bh0[c >> 1];
            const h2 bkB = bh1[c >> 1];
            H8 fa, fb;
            fa.h[0] = xh0[hh + 0] * bkA;  fa.h[1] = xh0[hh + 1] * bkA;
            fa.h[2] = xh0[hh + 2] * bkA;  fa.h[3] = xh0[hh + 3] * bkA;
            accA = __builtin_amdgcn_mfma_f32_16x16x32_f16(wf[c], fa.v, accA, 0, 0, 0);
            fb.h[0] = xh1[hh + 0] * bkB;  fb.h[1] = xh1[hh + 1] * bkB;
            fb.h[2] = xh1[hh + 2] * bkB;  fb.h[3] = xh1[hh + 3] * bkB;
            accB = __builtin_amdgcn_mfma_f32_16x16x32_f16(wf[c], fb.v, accB, 0, 0, 0);
        }
        __builtin_amdgcn_s_setprio(0);

        // ---- facet mean + bias + ReLU + stats + store (facet = 4 adjacent lanes)
        const int f0 = u * 8 + (col >> 2);
        EPI(accA, rc0, f0);
        EPI(accB, rc1, f0 + 4);
    };

    char* B0 = ldsbuf;
    char* B1 = ldsbuf + LDSP;
    char* B2 = ldsbuf + 2 * LDSP;

    // ---- software pipeline: 3-buffer rotation, stage(t) -> buffer read at t-1
    STAGE(B0, b);
    STAGE(B1, b + GRID1);
    WAITV(5); ITER(B0, B2, b,         b + 2 * GRID1, true);   // also drains wf prologue loads
    WAITV(7); ITER(B1, B0, b + GRID1, b + 3 * GRID1, true);
    char *rd = B2, *st = B1, *ot = B0;
    int t = 2;
    for (; t < n - 2; ++t) {
        WAITV(9);
        ITER(rd, st, b + t * GRID1, b + (t + 2) * GRID1, true);
        char* tmp = ot; ot = st; st = rd; rd = tmp;
    }
    WAITV(9); ITER(rd, st, b + t * GRID1, 0, false);
    { char* tmp = ot; ot = st; st = rd; rd = tmp; } ++t;
    WAITV(4); ITER(rd, st, b + t * GRID1, 0, false);

    // reduce stats across the 16 cols; channels partitioned by (wave,quad,r)
#pragma unroll
    for (int r = 0; r < 4; ++r) {
        float s = sacc[r], s2 = s2acc[r];
        s  += __shfl_xor(s, 1);  s  += __shfl_xor(s, 2);
        s  += __shfl_xor(s, 4);  s  += __shfl_xor(s, 8);
        s2 += __shfl_xor(s2, 1); s2 += __shfl_xor(s2, 2);
        s2 += __shfl_xor(s2, 4); s2 += __shfl_xor(s2, 8);
        if (col == 0) {
            sl_s [wave * 16 + quad * 4 + r] = s  * 0.25f;
            sl_s2[wave * 16 + quad * 4 + r] = s2 * 0.25f;
        }
    }
    __syncthreads();
    if (tid < 64)        atomicAdd(&stats[tid],      sl_s [tid]);
    else if (tid < 128)  atomicAdd(&stats[tid],      sl_s2[tid - 64]);
}

// ---- kernel 3: in-place batch-norm normalize on OUT
__global__ __launch_bounds__(256) void pass3_kernel(float* __restrict__ OUT,
    const float* __restrict__ stats, const float* __restrict__ gamma,
    const float* __restrict__ beta) {
    const int tid = threadIdx.x;
    const size_t l = (size_t)blockIdx.x * 256 + tid;
    const int c0 = ((int)l & 15) * 4;     // grid*256 is a multiple of 16 -> constant per thread
    float mu[4], sc[4], be[4];
    const float invF = 1.0f / (float)FFACETS;
#pragma unroll
    for (int u = 0; u < 4; ++u) {
        int ch = c0 + u;
        float m  = stats[ch] * invF;
        float va = stats[64 + ch] * invF - m * m;
        mu[u] = m;
        sc[u] = rsqrtf(va + 1e-3f) * gamma[ch];
        be[u] = beta[ch];
    }
    const size_t n4 = (size_t)FFACETS * 16;
    for (size_t i = l; i < n4; i += (size_t)gridDim.x * 256) {
        f32x4 v = ((f32x4*)OUT)[i];
#pragma unroll
        for (int u = 0; u < 4; ++u)
            v[u] = (v[u] - mu[u]) * sc[u] + be[u];
        ((f32x4*)OUT)[i] = v;
    }
}

extern "C" void kernel_launch(void* const* d_in, const int* in_sizes, int n_in,
                              void* d_out, int out_size, void* d_ws, size_t ws_size,
                              hipStream_t stream) {
    const float* X     = (const float*)d_in[0];
    const float* BARY  = (const float*)d_in[1];
    const float* W     = (const float*)d_in[2];
    const float* BIAS  = (const float*)d_in[3];
    const float* GAMMA = (const float*)d_in[4];
    const float* BETA  = (const float*)d_in[5];
    const int*   NTEX  = (const int*)d_in[6];
    float* OUT = (float*)d_out;

    _Float16* wswz = (_Float16*)d_ws;                       // 73728 B
    float* stats   = (float*)((char*)d_ws + 73728);         // 128 floats

    prep_kernel<<<144, 256, 0, stream>>>(W, wswz, stats);
    pass1_kernel<<<GRID1, 256, 0, stream>>>(X, BARY, wswz, BIAS, NTEX, OUT, stats);
    pass3_kernel<<<2048, 256, 0, stream>>>(OUT, stats, GAMMA, BETA);
}

// Round 13
// 655.573 us; speedup vs baseline: 1.2135x; 1.0158x over previous
//
#include <hip/hip_runtime.h>

// F2FConv3d on MI355X.
// V14: 32x32x16 MFMA restructure. Wave (wc=wave>>1, wt=wave&1) owns a 32ch x 32tex
// output tile; block processes 4 groups (64 tex) per iter. Per-texture VALU halves
// (B-build amortized over 32 ch), per-texture DS halves, MFMA cyc/FLOP -20% (8cy/32k
// vs 5cy/16k). wf A-frags = 36 x half8 = 144 AGPRs -> 2 waves/SIMD (256-reg budget;
// total ~240, no forced 170 cap = V7's spill cause avoided).
//
// K ordering per 32x32x16 chunk c (0..35): kb = c>>2, ci = (c&3)*16 + (lane>>5)*8 + j.
// A: row = lane&31 (channel), k as above (analog of the verified 16x16x32 layout).
// C/D (measured m74/m101): col = lane&31 (texture), row = (reg&3)+8*(reg>>2)+4*(lane>>5).
// Facet = 4 adjacent lanes -> DPP quad reduce (V13). Stats: lane q=lane&3 accumulates
// channel slice 8q+4hi+j -> zero overcount (quad lanes take disjoint slices).
//
// Pipeline (= V6 template): 3-buffer rotation, SINGLE barrier/iter (stage(t) targets
// buffer read at t-1), depth-2 counted vmcnt, NEVER 0 in loop. Ladder re-derived for
// [stage:6][stores:4]: prologue 6/10, steady 14, tail 14/8. X staged via global_load_lds,
// read-conflict-free via XOR-swizzled granule (g' = g ^ (tt&15)) applied on the global
// source (linear LDS dest, rule 21) and on the read address: 2 lanes/granule = free.

typedef _Float16 half8  __attribute__((ext_vector_type(8)));
typedef _Float16 h2     __attribute__((ext_vector_type(2)));
typedef __fp16   fp16x2 __attribute__((ext_vector_type(2)));
typedef float    f32x4  __attribute__((ext_vector_type(4)));
typedef float    f32x16 __attribute__((ext_vector_type(16)));

#define NQUADS  25000    // 100000 groups / 4 per block-iter
#define FFACETS 400000
#define GRID1   512      // 2 blocks/CU x 256 CUs
#define LDSP    18752    // per buffer: X[0,16384) | BARY[16384,18688) | NTEX[18688,18752)

#define WAITV(N) asm volatile("s_waitcnt vmcnt(" #N ")" ::: "memory")
#define WAITL0() asm volatile("s_waitcnt lgkmcnt(0)" ::: "memory")
#define FENCE()  asm volatile("" ::: "memory")

union H8 { h2 h[4]; half8 v; };

static __device__ __forceinline__ h2 pkrtz(float a, float b) {
    fp16x2 r = __builtin_amdgcn_cvt_pkrtz(a, b);
    return __builtin_bit_cast(h2, r);
}

// facet sum over the 4 adjacent lanes of a quad — VALU-pipe DPP, no DS traffic
static __device__ __forceinline__ float qsum(float s) {
    s += __builtin_bit_cast(float, __builtin_amdgcn_mov_dpp(
             __builtin_bit_cast(int, s), 0xB1, 0xF, 0xF, true));   // quad_perm [1,0,3,2]
    s += __builtin_bit_cast(float, __builtin_amdgcn_mov_dpp(
             __builtin_bit_cast(int, s), 0x4E, 0xF, 0xF, true));   // quad_perm [2,3,0,1]
    return s;
}

static __device__ __forceinline__ void gload16(const void* g, void* l) {
    __builtin_amdgcn_global_load_lds((const __attribute__((address_space(1))) void*)g,
                                     (__attribute__((address_space(3))) void*)l, 16, 0, 0);
}

// ---- kernel 1: swizzle W (fp32 [64][64][9]) -> 32x32x16 A-fragment order, zero stats
__global__ __launch_bounds__(256) void prep_kernel(const float* __restrict__ W,
                                                   _Float16* __restrict__ wswz,
                                                   float* __restrict__ stats) {
    int idx = blockIdx.x * 256 + threadIdx.x;
    if (idx < 36864) {
        int j    = idx & 7;
        int lane = (idx >> 3) & 63;
        int wc   = (idx >> 9) & 1;        // channel half
        int c    = idx >> 10;             // chunk 0..35
        int o    = wc * 32 + (lane & 31);
        int i    = (c & 3) * 16 + (lane >> 5) * 8 + j;
        int kb   = c >> 2;
        wswz[idx] = (_Float16)W[(o * 64 + i) * 9 + kb];
    }
    if (idx < 128) stats[idx] = 0.0f;
}

// ---- kernel 2: fused GEMM + facet mean + bias + ReLU + BN-stat accumulation
__global__ __launch_bounds__(256, 2) void pass1_kernel(
    const float* __restrict__ X, const float* __restrict__ BARY,
    const _Float16* __restrict__ WSWZ, const float* __restrict__ BIAS,
    const int* __restrict__ NTEX, float* __restrict__ OUT,
    float* __restrict__ stats) {

    __shared__ __align__(16) char ldsbuf[3 * LDSP];
    __shared__ float sl_s[128];
    __shared__ float sl_s2[128];
    __shared__ float sbias[64];

    const int tid  = threadIdx.x;
    const int wave = tid >> 6;
    const int lane = tid & 63;
    const int wc   = wave >> 1;   // channel half (0: ch 0-31, 1: ch 32-63)
    const int wt   = wave & 1;    // texture half (32 of the 64 textures)
    const int t    = lane & 31;   // texture within the wave's 32 (MFMA column)
    const int hi   = lane >> 5;
    const int q    = lane & 3;

    // bias -> LDS (all waves redundantly: uniform vmem count), 1 global + 1 ds_write
    sbias[lane] = BIAS[lane];
    WAITL0();

    // A-operand: 36 chunks x 4 VGPR = 144 AGPRs, resident whole kernel
    half8 wf[36];
#pragma unroll
    for (int c = 0; c < 36; ++c)
        wf[c] = *(const half8*)(WSWZ + ((size_t)(c * 2 + wc) * 64 + lane) * 8);

    // ---- stage-side: linear LDS dest, XOR-swizzled global src (granule ^= tt&15)
    int xsg[4];
#pragma unroll
    for (int i = 0; i < 4; ++i) {
        const int tt = wave * 16 + i * 4 + (lane >> 4);          // texture 0..63 in quad
        xsg[i] = tt * 256 + (((lane & 15) ^ (tt & 15)) << 4);
    }
    const int xd = wave * 4096 + lane * 16;                      // linear dest
    const char* Xb  = (const char*)X;
    const char* BAb = (const char*)BARY;
    const char* NTb = (const char*)NTEX;

    // ---- read-side: swizzled granule -> 2 lanes/granule = conflict-free b128
    int xr[8];
#pragma unroll
    for (int ciq = 0; ciq < 4; ++ciq)
#pragma unroll
        for (int jj = 0; jj < 2; ++jj)
            xr[ciq * 2 + jj] = (wt * 32 + t) * 256 +
                               (((ciq * 4 + hi * 2 + jj) ^ (lane & 15)) << 4);
    const int bco = 16384 + (wt * 2 + (t >> 4)) * 576 + (lane & 15) * 36;
    const int nco = 18688 + wt * 32 + ((t >> 2) << 2);

    float sacc[4]  = {0.f, 0.f, 0.f, 0.f};
    float s2acc[4] = {0.f, 0.f, 0.f, 0.f};

    const int b = blockIdx.x;
    const int n = (NQUADS - 1 - b) / GRID1 + 1;                  // quads for this block

    // 6 vmem ops per wave per STAGE (4 X quarters + bary group + ntex quad)
    auto STAGE = [&](char* S, int u) {
        const char* xs = Xb + (size_t)u * 16384;
        FENCE();
        gload16(xs + xsg[0], S + xd);
        gload16(xs + xsg[1], S + xd + 1024);
        gload16(xs + xsg[2], S + xd + 2048);
        gload16(xs + xsg[3], S + xd + 3072);
        if (lane < 36) gload16(BAb + (size_t)u * 2304 + wave * 576 + lane * 16,
                               S + 16384 + wave * 576 + lane * 16);
        if (lane < 1)  gload16(NTb + (size_t)u * 64 + wave * 16, S + 18688 + wave * 16);
        FENCE();
    };

    // ITER: [barrier][read L: 8 b128 X + 9 b32 bary + nt + bias][stage into S]
    //       [pack][36 MFMA single acc chain][qsum EPI + stats + 4 stores]
    auto ITER = [&](const char* L, char* S, int u, int upre, bool do_stage) {
        __builtin_amdgcn_s_barrier();      // caller did WAITV: stage(u) landed for all waves
        FENCE();
        f32x4 r[8];
#pragma unroll
        for (int k = 0; k < 8; ++k) r[k] = *(const f32x4*)(L + xr[k]);
        float bF[9];
#pragma unroll
        for (int k = 0; k < 9; ++k) bF[k] = *(const float*)(L + bco + k * 4);
        const int nt = *(const int*)(L + nco);
        f32x4 bias4[4];
#pragma unroll
        for (int qp = 0; qp < 4; ++qp)
            bias4[qp] = *(const f32x4*)&sbias[wc * 32 + hi * 4 + qp * 8];

        if (do_stage) STAGE(S, upre);      // flies across 2 iterations

        // pack x (16 pkrtz) and bary (9 pkrtz)
        h2 xh[16], bh[9];
#pragma unroll
        for (int k = 0; k < 8; ++k) {
            xh[k * 2]     = pkrtz(r[k][0], r[k][1]);
            xh[k * 2 + 1] = pkrtz(r[k][2], r[k][3]);
        }
#pragma unroll
        for (int k = 0; k < 9; ++k) bh[k] = pkrtz(bF[k], bF[k]);
        const float rc = __builtin_amdgcn_rcpf((float)nt);       // exact for pow2 counts

        // ---- 36 MFMAs, single 16-reg accumulator chain
        f32x16 acc = {};
        __builtin_amdgcn_s_setprio(1);
#pragma unroll
        for (int c = 0; c < 36; ++c) {
            const h2 bk = bh[c >> 2];
            const int xb = (c & 3) * 4;
            H8 bf;
            bf.h[0] = xh[xb + 0] * bk;  bf.h[1] = xh[xb + 1] * bk;
            bf.h[2] = xh[xb + 2] * bk;  bf.h[3] = xh[xb + 3] * bk;
            acc = __builtin_amdgcn_mfma_f32_32x32x16_f16(wf[c], bf.v, acc, 0, 0, 0);
        }
        __builtin_amdgcn_s_setprio(0);

        // ---- facet mean + bias + ReLU (rows: reg=qp*4+j -> ch = wc*32 + 4hi + 8qp + j)
        f32x4 vq[4];
#pragma unroll
        for (int qp = 0; qp < 4; ++qp)
#pragma unroll
            for (int j = 0; j < 4; ++j) {
                float s = qsum(acc[qp * 4 + j]);
                s = s * rc + bias4[qp][j];
                vq[qp][j] = s > 0.f ? s : 0.f;
            }

        // stats: lane q takes slice qp==q (disjoint across the quad -> no overcount)
#pragma unroll
        for (int j = 0; j < 4; ++j) {
            float p = vq[0][j];
            p = (q == 1) ? vq[1][j] : p;
            p = (q == 2) ? vq[2][j] : p;
            p = (q == 3) ? vq[3][j] : p;
            sacc[j]  += p;
            s2acc[j] += p * p;
        }

        const int f = u * 16 + wt * 8 + (t >> 2);
        if ((lane & 3) == 0) {
            float* op = OUT + (size_t)f * 64 + wc * 32 + hi * 4;
            *(f32x4*)(op)      = vq[0];
            *(f32x4*)(op + 8)  = vq[1];
            *(f32x4*)(op + 16) = vq[2];
            *(f32x4*)(op + 24) = vq[3];
        }
    };

    char* B0 = ldsbuf;
    char* B1 = ldsbuf + LDSP;
    char* B2 = ldsbuf + 2 * LDSP;

    // ---- software pipeline: 3-buffer rotation, counted vmcnt ([stage:6][stores:4])
    STAGE(B0, b);
    STAGE(B1, b + GRID1);
    WAITV(6);  ITER(B0, B2, b,         b + 2 * GRID1, true);   // drains bias+wf+stage0
    WAITV(10); ITER(B1, B0, b + GRID1, b + 3 * GRID1, true);
    char *rd = B2, *st = B1, *ot = B0;
    int tI = 2;
    for (; tI < n - 2; ++tI) {
        WAITV(14);
        ITER(rd, st, b + tI * GRID1, b + (tI + 2) * GRID1, true);
        char* tmp = ot; ot = st; st = rd; rd = tmp;
    }
    WAITV(14); ITER(rd, st, b + tI * GRID1, 0, false);
    { char* tmp = ot; ot = st; st = rd; rd = tmp; } ++tI;
    WAITV(8);  ITER(rd, st, b + tI * GRID1, 0, false);

    // ---- stats: reduce over the 8 facet-quads per wave (lane bits 2..4), then LDS+atomics
#pragma unroll
    for (int j = 0; j < 4; ++j) {
        float s = sacc[j], s2 = s2acc[j];
        s  += __shfl_xor(s, 4);   s  += __shfl_xor(s, 8);   s  += __shfl_xor(s, 16);
        s2 += __shfl_xor(s2, 4);  s2 += __shfl_xor(s2, 8);  s2 += __shfl_xor(s2, 16);
        if (((lane >> 2) & 7) == 0) {
            const int idx = wt * 64 + wc * 32 + hi * 4 + q * 8 + j;
            sl_s[idx]  = s;
            sl_s2[idx] = s2;
        }
    }
    __syncthreads();
    if (tid < 64)        atomicAdd(&stats[tid], sl_s[tid] + sl_s[tid + 64]);
    else if (tid < 128)  atomicAdd(&stats[tid], sl_s2[tid - 64] + sl_s2[tid]);
}

// ---- kernel 3: in-place batch-norm normalize on OUT
__global__ __launch_bounds__(256) void pass3_kernel(float* __restrict__ OUT,
    const float* __restrict__ stats, const float* __restrict__ gamma,
    const float* __restrict__ beta) {
    const int tid = threadIdx.x;
    const size_t l = (size_t)blockIdx.x * 256 + tid;
    const int c0 = ((int)l & 15) * 4;     // grid*256 is a multiple of 16 -> constant per thread
    float mu[4], sc[4], be[4];
    const float invF = 1.0f / (float)FFACETS;
#pragma unroll
    for (int u = 0; u < 4; ++u) {
        int ch = c0 + u;
        float m  = stats[ch] * invF;
        float va = stats[64 + ch] * invF - m * m;
        mu[u] = m;
        sc[u] = rsqrtf(va + 1e-3f) * gamma[ch];
        be[u] = beta[ch];
    }
    const size_t n4 = (size_t)FFACETS * 16;
    for (size_t i = l; i < n4; i += (size_t)gridDim.x * 256) {
        f32x4 v = ((f32x4*)OUT)[i];
#pragma unroll
        for (int u = 0; u < 4; ++u)
            v[u] = (v[u] - mu[u]) * sc[u] + be[u];
        ((f32x4*)OUT)[i] = v;
    }
}

extern "C" void kernel_launch(void* const* d_in, const int* in_sizes, int n_in,
                              void* d_out, int out_size, void* d_ws, size_t ws_size,
                              hipStream_t stream) {
    const float* X     = (const float*)d_in[0];
    const float* BARY  = (const float*)d_in[1];
    const float* W     = (const float*)d_in[2];
    const float* BIAS  = (const float*)d_in[3];
    const float* GAMMA = (const float*)d_in[4];
    const float* BETA  = (const float*)d_in[5];
    const int*   NTEX  = (const int*)d_in[6];
    float* OUT = (float*)d_out;

    _Float16* wswz = (_Float16*)d_ws;                       // 73728 B
    float* stats   = (float*)((char*)d_ws + 73728);         // 128 floats

    prep_kernel<<<144, 256, 0, stream>>>(W, wswz, stats);
    pass1_kernel<<<GRID1, 256, 0, stream>>>(X, BARY, wswz, BIAS, NTEX, OUT, stats);
    pass3_kernel<<<2048, 256, 0, stream>>>(OUT, stats, GAMMA, BETA);
}